// Round 2
// baseline (476.722 us; speedup 1.0000x reference)
//
#include <hip/hip_runtime.h>

#define BATCH 64
#define H 512
#define W 512
#define NR 256
#define ROWS_PER_BLOCK 16
#define THREADS 256

// Native HW fp32 atomics (ds_add_f32 / global_atomic_add_f32), no CAS loop.
__device__ __forceinline__ void lds_add(float* p, float v) {
    unsafeAtomicAdd(p, v);
}
__device__ __forceinline__ void glob_add(float* p, float v) {
    unsafeAtomicAdd(p, v);
}

// Accumulate kernel: each block handles ROWS_PER_BLOCK rows of one batch image.
// Per-thread: 4 consecutive x pixels (float4 loads from each of the 4 planes).
// Ring bin computed on the fly; run-length compressed flush into LDS atomics;
// block-level flush into global accumulators (d_ws) with atomicAdd.
__global__ __launch_bounds__(THREADS) void frc_accum(
    const float* __restrict__ f1r, const float* __restrict__ f1i,
    const float* __restrict__ f2r, const float* __restrict__ f2i,
    float* __restrict__ gacc /* [BATCH][NR][4] */)
{
    __shared__ float s_acc[NR * 4];
    for (int i = threadIdx.x; i < NR * 4; i += THREADS) s_acc[i] = 0.0f;
    __syncthreads();

    const int b    = blockIdx.y;
    const int row0 = blockIdx.x * ROWS_PER_BLOCK;
    const int tid  = threadIdx.x;
    const int x0   = (tid & 127) * 4;       // 128 threads cover one row
    const int rsub = tid >> 7;              // 0 or 1: two rows per pass

    for (int rp = 0; rp < ROWS_PER_BLOCK; rp += 2) {
        const int y = row0 + rp + rsub;
        const float fdy = (float)(y - 256);
        const float dy2 = fdy * fdy;
        const size_t base = ((size_t)b * H + (size_t)y) * W + (size_t)x0;

        const float4 v1r = *(const float4*)(f1r + base);
        const float4 v1i = *(const float4*)(f1i + base);
        const float4 v2r = *(const float4*)(f2r + base);
        const float4 v2i = *(const float4*)(f2i + base);

        const float a1[4] = {v1r.x, v1r.y, v1r.z, v1r.w};
        const float b1[4] = {v1i.x, v1i.y, v1i.z, v1i.w};
        const float a2[4] = {v2r.x, v2r.y, v2r.z, v2r.w};
        const float b2[4] = {v2i.x, v2i.y, v2i.z, v2i.w};

        float acr = 0.f, aci = 0.f, ap1 = 0.f, ap2 = 0.f;
        int cur = -1;

        #pragma unroll
        for (int j = 0; j < 4; ++j) {
            const float fdx = (float)(x0 + j - 256);
            const float r2  = fdx * fdx + dy2;     // exact: integer < 2^18
            const int bin   = (int)sqrtf(r2);      // floor(sqrt) safe in fp32

            // cross = F1 * conj(F2)
            const float cr = a1[j] * a2[j] + b1[j] * b2[j];
            const float ci = b1[j] * a2[j] - a1[j] * b2[j];
            const float p1 = a1[j] * a1[j] + b1[j] * b1[j];
            const float p2 = a2[j] * a2[j] + b2[j] * b2[j];

            if (bin != cur) {
                if (cur >= 0 && cur < NR) {
                    lds_add(&s_acc[cur * 4 + 0], acr);
                    lds_add(&s_acc[cur * 4 + 1], aci);
                    lds_add(&s_acc[cur * 4 + 2], ap1);
                    lds_add(&s_acc[cur * 4 + 3], ap2);
                }
                acr = 0.f; aci = 0.f; ap1 = 0.f; ap2 = 0.f;
                cur = bin;
            }
            acr += cr; aci += ci; ap1 += p1; ap2 += p2;
        }
        if (cur >= 0 && cur < NR) {
            lds_add(&s_acc[cur * 4 + 0], acr);
            lds_add(&s_acc[cur * 4 + 1], aci);
            lds_add(&s_acc[cur * 4 + 2], ap1);
            lds_add(&s_acc[cur * 4 + 3], ap2);
        }
    }

    __syncthreads();

    // One thread per ring: flush block-local sums to global accumulators.
    const int ring = tid;  // THREADS == NR
    const float scr = s_acc[ring * 4 + 0];
    const float sci = s_acc[ring * 4 + 1];
    const float sp1 = s_acc[ring * 4 + 2];
    const float sp2 = s_acc[ring * 4 + 3];
    if (scr != 0.f || sci != 0.f || sp1 != 0.f || sp2 != 0.f) {
        float* g = gacc + (((size_t)b * NR) + ring) * 4;
        glob_add(&g[0], scr);
        glob_add(&g[1], sci);
        glob_add(&g[2], sp1);
        glob_add(&g[3], sp2);
    }
}

__global__ __launch_bounds__(NR) void frc_finalize(
    const float* __restrict__ gacc, float* __restrict__ out)
{
    const int b = blockIdx.x;
    const int r = threadIdx.x;
    const float* g = gacc + (((size_t)b * NR) + r) * 4;
    const float cr = g[0], ci = g[1], p1 = g[2], p2 = g[3];
    const float num = sqrtf(cr * cr + ci * ci);
    const float den = sqrtf(p1 * p2);
    out[(size_t)b * NR + r] = (den == 0.f) ? 0.f : num / den;
}

extern "C" void kernel_launch(void* const* d_in, const int* in_sizes, int n_in,
                              void* d_out, int out_size, void* d_ws, size_t ws_size,
                              hipStream_t stream) {
    const float* f1r = (const float*)d_in[0];
    const float* f1i = (const float*)d_in[1];
    const float* f2r = (const float*)d_in[2];
    const float* f2i = (const float*)d_in[3];
    float* out  = (float*)d_out;
    float* gacc = (float*)d_ws;   // BATCH*NR*4 floats = 256 KiB

    (void)in_sizes; (void)n_in; (void)out_size; (void)ws_size;

    hipMemsetAsync(gacc, 0, (size_t)BATCH * NR * 4 * sizeof(float), stream);

    dim3 grid(H / ROWS_PER_BLOCK, BATCH);  // 32 x 64 = 2048 blocks
    frc_accum<<<grid, THREADS, 0, stream>>>(f1r, f1i, f2r, f2i, gacc);
    frc_finalize<<<dim3(BATCH), dim3(NR), 0, stream>>>(gacc, out);
}

// Round 3
// 474.256 us; speedup vs baseline: 1.0052x; 1.0052x over previous
//
#include <hip/hip_runtime.h>
#include <stdint.h>

#define BATCH 64
#define H 512
#define W 512
#define NR 256
#define ROWS_PER_BLOCK 16
#define THREADS 256
#define NWAVE 4

// LDS aperture is 4 GiB-aligned on gfx9: low 32 bits of a generic pointer to
// __shared__ memory are exactly the LDS byte offset.
__device__ __forceinline__ uint32_t lds_off(const void* p) {
    return (uint32_t)(uintptr_t)p;
}

// Native, fire-and-forget LDS fp32 adds to 4 component tables spaced 1 KiB
// apart (NR * 4 bytes). No CAS loop possible.
__device__ __forceinline__ void lds_add4(uint32_t addr, float v0, float v1,
                                         float v2, float v3) {
    asm volatile(
        "ds_add_f32 %0, %1\n\t"
        "ds_add_f32 %0, %2 offset:1024\n\t"
        "ds_add_f32 %0, %3 offset:2048\n\t"
        "ds_add_f32 %0, %4 offset:3072"
        :: "v"(addr), "v"(v0), "v"(v1), "v"(v2), "v"(v3) : "memory");
}

// Native global fp32 atomic add, no return value.
__device__ __forceinline__ void gl_add(float* p, float v) {
    asm volatile("global_atomic_add_f32 %0, %1, off"
                 :: "v"(p), "v"(v) : "memory");
}

__global__ __launch_bounds__(THREADS) void frc_accum(
    const float* __restrict__ f1r, const float* __restrict__ f1i,
    const float* __restrict__ f2r, const float* __restrict__ f2i,
    float* __restrict__ gacc /* [BATCH][4][NR] */)
{
    __shared__ float s_acc[NWAVE * 4 * NR];   // [wave][comp][ring], 16 KiB
    for (int i = threadIdx.x; i < NWAVE * 4 * NR; i += THREADS) s_acc[i] = 0.0f;
    __syncthreads();

    const int b    = blockIdx.y;
    const int row0 = blockIdx.x * ROWS_PER_BLOCK;
    const int tid  = threadIdx.x;
    const int x0   = (tid & 127) * 4;       // 128 threads cover one row
    const int rsub = tid >> 7;              // 0 or 1: two rows per pass
    const int wid  = tid >> 6;              // private LDS table per wave
    const uint32_t wbase = lds_off(&s_acc[wid * 4 * NR]);

    for (int rp = 0; rp < ROWS_PER_BLOCK; rp += 2) {
        const int y = row0 + rp + rsub;
        const float fdy = (float)(y - 256);
        const float dy2 = fdy * fdy;
        const size_t base = ((size_t)b * H + (size_t)y) * W + (size_t)x0;

        const float4 v1r = *(const float4*)(f1r + base);
        const float4 v1i = *(const float4*)(f1i + base);
        const float4 v2r = *(const float4*)(f2r + base);
        const float4 v2i = *(const float4*)(f2i + base);

        const float a1[4] = {v1r.x, v1r.y, v1r.z, v1r.w};
        const float b1[4] = {v1i.x, v1i.y, v1i.z, v1i.w};
        const float a2[4] = {v2r.x, v2r.y, v2r.z, v2r.w};
        const float b2[4] = {v2i.x, v2i.y, v2i.z, v2i.w};

        float acr = 0.f, aci = 0.f, ap1 = 0.f, ap2 = 0.f;
        int cur = -1;

        #pragma unroll
        for (int j = 0; j < 4; ++j) {
            const float fdx = (float)(x0 + j - 256);
            const float r2  = fdx * fdx + dy2;     // exact: integer < 2^18
            const int bin   = (int)sqrtf(r2);      // floor(sqrt) safe in fp32

            // cross = F1 * conj(F2)
            const float cr = a1[j] * a2[j] + b1[j] * b2[j];
            const float ci = b1[j] * a2[j] - a1[j] * b2[j];
            const float p1 = a1[j] * a1[j] + b1[j] * b1[j];
            const float p2 = a2[j] * a2[j] + b2[j] * b2[j];

            if (bin != cur) {
                if (cur >= 0 && cur < NR)
                    lds_add4(wbase + 4u * (uint32_t)cur, acr, aci, ap1, ap2);
                acr = 0.f; aci = 0.f; ap1 = 0.f; ap2 = 0.f;
                cur = bin;
            }
            acr += cr; aci += ci; ap1 += p1; ap2 += p2;
        }
        if (cur >= 0 && cur < NR)
            lds_add4(wbase + 4u * (uint32_t)cur, acr, aci, ap1, ap2);
    }

    // Compiler can't see the asm's outstanding LDS ops — drain before barrier.
    asm volatile("s_waitcnt lgkmcnt(0)" ::: "memory");
    __syncthreads();

    // Merge the 4 wave-private tables; one thread per ring. Stride-1 reads,
    // conflict-free.
    const int r = tid;  // THREADS == NR
    float s0 = 0.f, s1 = 0.f, s2 = 0.f, s3 = 0.f;
    #pragma unroll
    for (int w = 0; w < NWAVE; ++w) {
        const float* tb = &s_acc[w * 4 * NR];
        s0 += tb[0 * NR + r];
        s1 += tb[1 * NR + r];
        s2 += tb[2 * NR + r];
        s3 += tb[3 * NR + r];
    }
    if (s0 != 0.f || s1 != 0.f || s2 != 0.f || s3 != 0.f) {
        float* g = gacc + ((size_t)b * 4) * NR + r;
        gl_add(g + 0 * NR, s0);
        gl_add(g + 1 * NR, s1);
        gl_add(g + 2 * NR, s2);
        gl_add(g + 3 * NR, s3);
    }
}

__global__ __launch_bounds__(NR) void frc_finalize(
    const float* __restrict__ gacc, float* __restrict__ out)
{
    const int b = blockIdx.x;
    const int r = threadIdx.x;
    const float* g = gacc + (size_t)b * 4 * NR + r;
    const float cr = g[0 * NR], ci = g[1 * NR], p1 = g[2 * NR], p2 = g[3 * NR];
    const float num = sqrtf(cr * cr + ci * ci);
    const float den = sqrtf(p1 * p2);
    out[(size_t)b * NR + r] = (den == 0.f) ? 0.f : num / den;
}

extern "C" void kernel_launch(void* const* d_in, const int* in_sizes, int n_in,
                              void* d_out, int out_size, void* d_ws, size_t ws_size,
                              hipStream_t stream) {
    const float* f1r = (const float*)d_in[0];
    const float* f1i = (const float*)d_in[1];
    const float* f2r = (const float*)d_in[2];
    const float* f2i = (const float*)d_in[3];
    float* out  = (float*)d_out;
    float* gacc = (float*)d_ws;   // BATCH*4*NR floats = 256 KiB

    (void)in_sizes; (void)n_in; (void)out_size; (void)ws_size;

    hipMemsetAsync(gacc, 0, (size_t)BATCH * 4 * NR * sizeof(float), stream);

    dim3 grid(H / ROWS_PER_BLOCK, BATCH);  // 32 x 64 = 2048 blocks
    frc_accum<<<grid, THREADS, 0, stream>>>(f1r, f1i, f2r, f2i, gacc);
    frc_finalize<<<dim3(BATCH), dim3(NR), 0, stream>>>(gacc, out);
}